// Round 6
// baseline (535.415 us; speedup 1.0000x reference)
//
#include <hip/hip_runtime.h>

#define N_NODES 100000
#define N_EDGES 1600000
#define DIM_IN  128
#define DIM_H   256
#define DIM_C   40

#define NB   391     // buckets of 256 nodes
#define NBLK 391     // edge chunks of 4096
#define CHUNK 4096

typedef unsigned short bf16_t;
typedef __attribute__((ext_vector_type(8))) short short8;
typedef __attribute__((ext_vector_type(4))) float f32x4;

__device__ __forceinline__ bf16_t f2b(float f) {
    unsigned int u = __float_as_uint(f);
    unsigned int r = (u + 0x7fffu + ((u >> 16) & 1u)) >> 16;
    return (bf16_t)r;
}
__device__ __forceinline__ float b2f(unsigned int h16) {
    return __uint_as_float(h16 << 16);
}

__device__ __forceinline__ void gl_lds16(const void* gsrc, void* ldst) {
    __builtin_amdgcn_global_load_lds(
        (const __attribute__((address_space(1))) void*)gsrc,
        (__attribute__((address_space(3))) void*)ldst,
        16, 0, 0);
}

// ---------------- CSR build, two-phase binned ----------------

__global__ void k_bhist(const int* __restrict__ dst, int* __restrict__ cnt2, int e) {
    __shared__ int h[NB];
    int t = threadIdx.x, blk = blockIdx.x;
    for (int i = t; i < NB; i += 256) h[i] = 0;
    __syncthreads();
    int base = blk * CHUNK;
    int end = min(base + CHUNK, e);
    for (int i = base + t; i < end; i += 256)
        atomicAdd(&h[dst[i] >> 8], 1);
    __syncthreads();
    for (int i = t; i < NB; i += 256) cnt2[blk * NB + i] = h[i];
}

__global__ void k_bscanA(const int* __restrict__ cnt2, int* __restrict__ basep,
                         int* __restrict__ btot) {
    __shared__ int s[512];
    int t = threadIdx.x, b = blockIdx.x;
    int v = (t < NBLK) ? cnt2[t * NB + b] : 0;
    s[t] = v;
    __syncthreads();
    #pragma unroll
    for (int d = 1; d < 512; d <<= 1) {
        int tv = (t >= d) ? s[t - d] : 0;
        __syncthreads();
        s[t] += tv;
        __syncthreads();
    }
    if (t < NBLK) basep[t * NB + b] = s[t] - v;
    if (t == 511) btot[b] = s[511];
}

__global__ void k_bscan2(const int* __restrict__ btot, int* __restrict__ boff) {
    __shared__ int s[512];
    int t = threadIdx.x;
    int v = (t < NB) ? btot[t] : 0;
    s[t] = v;
    __syncthreads();
    #pragma unroll
    for (int d = 1; d < 512; d <<= 1) {
        int tv = (t >= d) ? s[t - d] : 0;
        __syncthreads();
        s[t] += tv;
        __syncthreads();
    }
    if (t < NB) boff[t] = s[t] - v;
    if (t == NB - 1) boff[NB] = s[t];
}

__global__ void k_bscatter(const int* __restrict__ src, const int* __restrict__ dst,
                           const int* __restrict__ basep, const int* __restrict__ boff,
                           int2* __restrict__ ebuf, int e) {
    __shared__ int cur[NB];
    int t = threadIdx.x, blk = blockIdx.x;
    for (int i = t; i < NB; i += 256) cur[i] = basep[blk * NB + i] + boff[i];
    __syncthreads();
    int base = blk * CHUNK;
    int end = min(base + CHUNK, e);
    for (int i = base + t; i < end; i += 256) {
        int sv = src[i], dv = dst[i];
        int pos = atomicAdd(&cur[dv >> 8], 1);
        ebuf[pos] = make_int2(sv, dv);
    }
}

// fused: per-bucket node-degree histogram + block-level inclusive scan
// (replaces k_bh + k_scan1; bucket == scan block == 256 nodes)
__global__ void k_bh_scan(const int2* __restrict__ ebuf, const int* __restrict__ boff,
                          int* __restrict__ off, int* __restrict__ bsum) {
    __shared__ int h[256];
    int t = threadIdx.x, b = blockIdx.x;
    h[t] = 0;
    __syncthreads();
    int e0 = boff[b], e1 = boff[b + 1];
    int node0 = b << 8;
    for (int i = e0 + t; i < e1; i += 256)
        atomicAdd(&h[ebuf[i].y - node0], 1);
    __syncthreads();
    // inclusive scan of h[0..255]
    #pragma unroll
    for (int d = 1; d < 256; d <<= 1) {
        int tv = (t >= d) ? h[t - d] : 0;
        __syncthreads();
        h[t] += tv;
        __syncthreads();
    }
    int node = node0 + t;
    if (node < N_NODES) off[node + 1] = h[t];
    if (t == 255) bsum[b] = h[255];
}

__global__ void k_scan2(int* __restrict__ bsum, int nb) {
    __shared__ int s[512];
    int v = ((int)threadIdx.x < nb) ? bsum[threadIdx.x] : 0;
    s[threadIdx.x] = v;
    __syncthreads();
    #pragma unroll
    for (int d = 1; d < 512; d <<= 1) {
        int t = (threadIdx.x >= d) ? s[threadIdx.x - d] : 0;
        __syncthreads();
        s[threadIdx.x] += t;
        __syncthreads();
    }
    if ((int)threadIdx.x < nb) bsum[threadIdx.x] = s[threadIdx.x];
}

__global__ void k_scan3(int* __restrict__ off, const int* __restrict__ bsum, int n) {
    int i = blockIdx.x * 256 + threadIdx.x;
    if (blockIdx.x > 0 && i < n) off[i + 1] += bsum[blockIdx.x - 1];
    if (i == 0) off[0] = 0;
}

__global__ void k_fscatter(const int2* __restrict__ ebuf, const int* __restrict__ boff,
                           const int* __restrict__ off, int* __restrict__ csr) {
    __shared__ int cur[256];
    int t = threadIdx.x, b = blockIdx.x;
    int node0 = b << 8;
    int node = node0 + t;
    cur[t] = (node < N_NODES) ? off[node] : 0;
    __syncthreads();
    int e0 = boff[b], e1 = boff[b + 1];
    for (int i = e0 + t; i < e1; i += 256) {
        int2 p = ebuf[i];
        int pos = atomicAdd(&cur[p.y - node0], 1);
        csr[pos] = p.x;
    }
}

// ---------------- converts ----------------

__global__ void k_cvt4(const float* __restrict__ in, bf16_t* __restrict__ out, int n4) {
    int i = blockIdx.x * 256 + threadIdx.x;
    if (i < n4) {
        float4 v = ((const float4*)in)[i];
        ushort4 o;
        o.x = f2b(v.x); o.y = f2b(v.y); o.z = f2b(v.z); o.w = f2b(v.w);
        ((ushort4*)out)[i] = o;
    }
}

__global__ void k_wt(const float* __restrict__ in, bf16_t* __restrict__ out,
                     int K, int N, int Npad) {
    int k = blockIdx.x * 256 + threadIdx.x;
    int n = blockIdx.y;
    if (k < K) {
        float v = (n < N) ? in[(size_t)k * N + n] : 0.f;
        out[(size_t)n * K + k] = f2b(v);
    }
}

// ---------------- aggregation (bf16 rows, fp32 accumulate, bf16 out) ----------------
// one wave per node; 8-deep batched edge loop (MLP) — at external-BW floor (R4/R5)

template <int D>
__global__ void k_agg_b(const bf16_t* __restrict__ h, const int* __restrict__ off,
                        const int* __restrict__ csr, const float* __restrict__ eps_p,
                        bf16_t* __restrict__ rst, int n) {
    constexpr int V = D / 64;  // 2 or 4
    int gid = blockIdx.x * blockDim.x + threadIdx.x;
    int u = gid >> 6;
    int lane = gid & 63;
    if (u >= n) return;

    float acc[V];
    #pragma unroll
    for (int j = 0; j < V; j++) acc[j] = 0.f;

    int r0 = off[u], r1 = off[u + 1];
    int r = r0;

    if constexpr (V == 2) {
        for (; r + 8 <= r1; r += 8) {
            int s[8];
            #pragma unroll
            for (int t = 0; t < 8; t++) s[t] = csr[r + t];
            unsigned int v[8];
            #pragma unroll
            for (int t = 0; t < 8; t++)
                v[t] = *(const unsigned int*)(h + (size_t)s[t] * D + lane * 2);
            #pragma unroll
            for (int t = 0; t < 8; t++) {
                acc[0] += b2f(v[t] & 0xffffu);
                acc[1] += b2f(v[t] >> 16);
            }
        }
        for (; r < r1; r++) {
            int s = csr[r];
            unsigned int v = *(const unsigned int*)(h + (size_t)s * D + lane * 2);
            acc[0] += b2f(v & 0xffffu);
            acc[1] += b2f(v >> 16);
        }
    } else {
        for (; r + 8 <= r1; r += 8) {
            int s[8];
            #pragma unroll
            for (int t = 0; t < 8; t++) s[t] = csr[r + t];
            uint2 v[8];
            #pragma unroll
            for (int t = 0; t < 8; t++)
                v[t] = *(const uint2*)(h + (size_t)s[t] * D + lane * 4);
            #pragma unroll
            for (int t = 0; t < 8; t++) {
                acc[0] += b2f(v[t].x & 0xffffu);
                acc[1] += b2f(v[t].x >> 16);
                acc[2] += b2f(v[t].y & 0xffffu);
                acc[3] += b2f(v[t].y >> 16);
            }
        }
        for (; r < r1; r++) {
            int s = csr[r];
            uint2 v = *(const uint2*)(h + (size_t)s * D + lane * 4);
            acc[0] += b2f(v.x & 0xffffu);
            acc[1] += b2f(v.x >> 16);
            acc[2] += b2f(v.y & 0xffffu);
            acc[3] += b2f(v.y >> 16);
        }
    }

    float ep = 1.0f + eps_p[0];
    const bf16_t* xrow = h + (size_t)u * D + lane * V;
    bf16_t* orow = rst + (size_t)u * D + lane * V;
    if constexpr (V == 2) {
        unsigned int v = *(const unsigned int*)xrow;
        float o0 = ep * b2f(v & 0xffffu) + acc[0];
        float o1 = ep * b2f(v >> 16) + acc[1];
        *(unsigned int*)orow = (unsigned int)f2b(o0) | ((unsigned int)f2b(o1) << 16);
    } else {
        uint2 v = *(const uint2*)xrow;
        float o0 = ep * b2f(v.x & 0xffffu) + acc[0];
        float o1 = ep * b2f(v.x >> 16) + acc[1];
        float o2 = ep * b2f(v.y & 0xffffu) + acc[2];
        float o3 = ep * b2f(v.y >> 16) + acc[3];
        uint2 ov;
        ov.x = (unsigned int)f2b(o0) | ((unsigned int)f2b(o1) << 16);
        ov.y = (unsigned int)f2b(o2) | ((unsigned int)f2b(o3) << 16);
        *(uint2*)orow = ov;
    }
}

// ---------------- fused 2-GEMM MLP: H = relu(relu(A@W1)@W2) ----------------
// 512 threads = 8 waves; block computes 128 rows x 256 cols.
// Phase 1: t = relu(A_block @ W1) -> Ts (LDS, bf16, 264-stride pad).
// Phase 2: H = relu(Ts @ W2), A-fragments from LDS.
// W1t: [256][K1] bf16 (transposed), W2t: [256][256] bf16 (transposed).

#define TS_STRIDE 264   // 256 + 8: keeps 16B alignment, rows rotate banks (2-way max)

template <int K1>
__global__ __launch_bounds__(512) void k_mlp(
    const bf16_t* __restrict__ A, const bf16_t* __restrict__ W1t,
    const bf16_t* __restrict__ W2t, bf16_t* __restrict__ H, int M)
{
    __shared__ __align__(16) bf16_t As[128 * 32];       // 8 KB
    __shared__ __align__(16) bf16_t Bs[256 * 32];       // 16 KB
    __shared__ __align__(16) bf16_t Ts[128 * TS_STRIDE];// 67.6 KB

    int tid = threadIdx.x;
    int wave = tid >> 6, lane = tid & 63;
    int l15 = lane & 15, quad = lane >> 4;
    int bm = blockIdx.x * 128;
    int wm = (wave >> 2) * 64, wn = (wave & 3) * 64;

    f32x4 acc[4][4];
    #pragma unroll
    for (int i = 0; i < 4; i++)
        #pragma unroll
        for (int j = 0; j < 4; j++) acc[i][j] = 0.f;

    // ---- phase 1: t = relu(A @ W1) ----
    for (int k0 = 0; k0 < K1; k0 += 32) {
        // stage A tile 128x32 (one 16B seg per thread)
        {
            int s = tid;
            int row = s >> 2, k8 = (s & 3) * 8;
            int gr = bm + row; if (gr >= M) gr = M - 1;
            gl_lds16(A + (size_t)gr * K1 + k0 + k8, &As[(size_t)(wave * 64) * 8]);
        }
        // stage W1t tile 256x32 (two 16B segs per thread)
        #pragma unroll
        for (int l = 0; l < 2; l++) {
            int s = tid + l * 512;
            int row = s >> 2, k8 = (s & 3) * 8;
            gl_lds16(W1t + (size_t)row * K1 + k0 + k8, &Bs[(size_t)(l * 512 + wave * 64) * 8]);
        }
        __syncthreads();

        short8 af[4], bfv[4];
        #pragma unroll
        for (int i = 0; i < 4; i++)
            af[i] = *(const short8*)&As[(wm + i * 16 + l15) * 32 + quad * 8];
        #pragma unroll
        for (int j = 0; j < 4; j++)
            bfv[j] = *(const short8*)&Bs[(wn + j * 16 + l15) * 32 + quad * 8];

        #pragma unroll
        for (int i = 0; i < 4; i++)
            #pragma unroll
            for (int j = 0; j < 4; j++)
                acc[i][j] = __builtin_amdgcn_mfma_f32_16x16x32_bf16(af[i], bfv[j], acc[i][j], 0, 0, 0);
        __syncthreads();
    }

    // write relu(t) to Ts as bf16; C-layout: row = quad*4+r, col = l15
    #pragma unroll
    for (int i = 0; i < 4; i++)
        #pragma unroll
        for (int j = 0; j < 4; j++) {
            int row = wm + i * 16 + quad * 4;
            int col = wn + j * 16 + l15;
            #pragma unroll
            for (int r = 0; r < 4; r++)
                Ts[(row + r) * TS_STRIDE + col] = f2b(fmaxf(acc[i][j][r], 0.f));
        }

    #pragma unroll
    for (int i = 0; i < 4; i++)
        #pragma unroll
        for (int j = 0; j < 4; j++) acc[i][j] = 0.f;
    __syncthreads();

    // ---- phase 2: H = relu(Ts @ W2) ----
    for (int k0 = 0; k0 < 256; k0 += 32) {
        #pragma unroll
        for (int l = 0; l < 2; l++) {
            int s = tid + l * 512;
            int row = s >> 2, k8 = (s & 3) * 8;
            gl_lds16(W2t + (size_t)row * 256 + k0 + k8, &Bs[(size_t)(l * 512 + wave * 64) * 8]);
        }
        __syncthreads();

        short8 af[4], bfv[4];
        #pragma unroll
        for (int i = 0; i < 4; i++)
            af[i] = *(const short8*)&Ts[(wm + i * 16 + l15) * TS_STRIDE + k0 + quad * 8];
        #pragma unroll
        for (int j = 0; j < 4; j++)
            bfv[j] = *(const short8*)&Bs[(wn + j * 16 + l15) * 32 + quad * 8];

        #pragma unroll
        for (int i = 0; i < 4; i++)
            #pragma unroll
            for (int j = 0; j < 4; j++)
                acc[i][j] = __builtin_amdgcn_mfma_f32_16x16x32_bf16(af[i], bfv[j], acc[i][j], 0, 0, 0);
        __syncthreads();
    }

    // epilogue: relu, bf16 store
    #pragma unroll
    for (int j = 0; j < 4; j++) {
        int col = wn + j * 16 + l15;
        #pragma unroll
        for (int i = 0; i < 4; i++) {
            #pragma unroll
            for (int r = 0; r < 4; r++) {
                int rowg = bm + wm + i * 16 + quad * 4 + r;
                if (rowg < M)
                    H[(size_t)rowg * 256 + col] = f2b(fmaxf(acc[i][j][r], 0.f));
            }
        }
    }
}

// ---------------- fc GEMM (m97 structure, 256 threads) ----------------

__global__ __launch_bounds__(256) void gemm_fc(
    const bf16_t* __restrict__ A, const bf16_t* __restrict__ Bt,
    const float* __restrict__ bias, float* __restrict__ C,
    int M, int K, int Nst)
{
    __shared__ __align__(16) bf16_t As[128 * 32];
    __shared__ __align__(16) bf16_t Bs[128 * 32];

    int tid = threadIdx.x;
    int wave = tid >> 6, lane = tid & 63;
    int l15 = lane & 15, quad = lane >> 4;
    int bm = blockIdx.y * 128, bn = blockIdx.x * 128;
    int wm = (wave >> 1) * 64, wn = (wave & 1) * 64;

    f32x4 acc[4][4];
    #pragma unroll
    for (int i = 0; i < 4; i++)
        #pragma unroll
        for (int j = 0; j < 4; j++) acc[i][j] = 0.f;

    for (int k0 = 0; k0 < K; k0 += 32) {
        #pragma unroll
        for (int iss = 0; iss < 2; iss++) {
            int s = iss * 256 + wave * 64 + lane;
            int row = s >> 2;
            int k8 = (s & 3) * 8;
            int ldsoff = (iss * 256 + wave * 64) * 8;

            int grA = bm + row; if (grA >= M) grA = M - 1;
            gl_lds16(A + (size_t)grA * K + k0 + k8, &As[ldsoff]);

            int grB = bn + row;
            gl_lds16(Bt + (size_t)grB * K + k0 + k8, &Bs[ldsoff]);
        }
        __syncthreads();

        short8 af[4], bfv[4];
        #pragma unroll
        for (int i = 0; i < 4; i++)
            af[i] = *(const short8*)&As[(wm + i * 16 + l15) * 32 + quad * 8];
        #pragma unroll
        for (int j = 0; j < 4; j++)
            bfv[j] = *(const short8*)&Bs[(wn + j * 16 + l15) * 32 + quad * 8];

        #pragma unroll
        for (int i = 0; i < 4; i++)
            #pragma unroll
            for (int j = 0; j < 4; j++)
                acc[i][j] = __builtin_amdgcn_mfma_f32_16x16x32_bf16(af[i], bfv[j], acc[i][j], 0, 0, 0);
        __syncthreads();
    }

    #pragma unroll
    for (int j = 0; j < 4; j++) {
        int col = bn + wn + j * 16 + l15;
        if (col >= Nst) continue;
        float bv = bias[col];
        #pragma unroll
        for (int i = 0; i < 4; i++) {
            #pragma unroll
            for (int r = 0; r < 4; r++) {
                int rowg = bm + wm + i * 16 + quad * 4 + r;
                if (rowg < M)
                    C[(size_t)rowg * Nst + col] = acc[i][j][r] + bv;
            }
        }
    }
}

// ---------------- launch ----------------

static inline size_t rnd256(size_t x) { return (x + 255) & ~(size_t)255; }

extern "C" void kernel_launch(void* const* d_in, const int* in_sizes, int n_in,
                              void* d_out, int out_size, void* d_ws, size_t ws_size,
                              hipStream_t stream) {
    const float* x    = (const float*)d_in[0];
    const int*   src  = (const int*)d_in[1];
    const int*   dst  = (const int*)d_in[2];
    const float* eps1 = (const float*)d_in[3];
    const float* w1a  = (const float*)d_in[4];
    const float* w1b  = (const float*)d_in[5];
    const float* eps2 = (const float*)d_in[6];
    const float* w2a  = (const float*)d_in[7];
    const float* w2b  = (const float*)d_in[8];
    const float* fc_w = (const float*)d_in[9];
    const float* fc_b = (const float*)d_in[10];
    float* out = (float*)d_out;

    char* w = (char*)d_ws;
    int* off  = (int*)w; w += rnd256(sizeof(int) * (size_t)(N_NODES + 1));
    int* bsum = (int*)w; w += rnd256(sizeof(int) * 1024);
    int* csr  = (int*)w; w += rnd256(sizeof(int) * (size_t)N_EDGES);
    int* cnt2  = (int*)w; w += rnd256(sizeof(int) * (size_t)NBLK * NB);
    int* basep = (int*)w; w += rnd256(sizeof(int) * (size_t)NBLK * NB);
    int* btot  = (int*)w; w += rnd256(sizeof(int) * 512);
    int* boff  = (int*)w; w += rnd256(sizeof(int) * (NB + 1));
    bf16_t* w1a_t = (bf16_t*)w; w += rnd256(2 * (size_t)DIM_H * DIM_IN);
    bf16_t* w1b_t = (bf16_t*)w; w += rnd256(2 * (size_t)DIM_H * DIM_H);
    bf16_t* w2a_t = (bf16_t*)w; w += rnd256(2 * (size_t)DIM_H * DIM_H);
    bf16_t* w2b_t = (bf16_t*)w; w += rnd256(2 * (size_t)DIM_H * DIM_H);
    bf16_t* fc_t  = (bf16_t*)w; w += rnd256(2 * (size_t)128 * DIM_H);
    bf16_t* R12 = (bf16_t*)w; w += rnd256(2 * (size_t)N_NODES * DIM_H);
    bf16_t* R3  = (bf16_t*)w; w += rnd256(2 * (size_t)N_NODES * DIM_H);

    bf16_t* xb   = R12;                             // [N][128]
    bf16_t* rst1 = R12 + (size_t)N_NODES * DIM_IN;  // [N][128]
    int2* ebuf = (int2*)R3;   // dead before k_mlp writes R3

    const int nb = (N_NODES + 255) / 256;

    // ---- CSR build: two-phase binned ----
    k_bhist<<<NBLK, 256, 0, stream>>>(dst, cnt2, N_EDGES);
    k_bscanA<<<NB, 512, 0, stream>>>(cnt2, basep, btot);
    k_bscan2<<<1, 512, 0, stream>>>(btot, boff);
    k_bscatter<<<NBLK, 256, 0, stream>>>(src, dst, basep, boff, ebuf, N_EDGES);
    k_bh_scan<<<NB, 256, 0, stream>>>(ebuf, boff, off, bsum);
    k_scan2<<<1, 512, 0, stream>>>(bsum, nb);
    k_scan3<<<nb, 256, 0, stream>>>(off, bsum, N_NODES);
    k_fscatter<<<NB, 256, 0, stream>>>(ebuf, boff, off, csr);

    // ---- converts ----
    k_cvt4<<<(N_NODES * DIM_IN / 4 + 255) / 256, 256, 0, stream>>>(x, xb, N_NODES * DIM_IN / 4);
    { dim3 g((DIM_IN + 255) / 256, DIM_H);  k_wt<<<g, 256, 0, stream>>>(w1a, w1a_t, DIM_IN, DIM_H, DIM_H); }
    { dim3 g((DIM_H + 255) / 256, DIM_H);   k_wt<<<g, 256, 0, stream>>>(w1b, w1b_t, DIM_H, DIM_H, DIM_H); }
    { dim3 g((DIM_H + 255) / 256, DIM_H);   k_wt<<<g, 256, 0, stream>>>(w2a, w2a_t, DIM_H, DIM_H, DIM_H); }
    { dim3 g((DIM_H + 255) / 256, DIM_H);   k_wt<<<g, 256, 0, stream>>>(w2b, w2b_t, DIM_H, DIM_H, DIM_H); }
    { dim3 g((DIM_H + 255) / 256, 128);     k_wt<<<g, 256, 0, stream>>>(fc_w, fc_t, DIM_H, DIM_C, 128); }

    const int agg_blocks = (N_NODES * 64 + 255) / 256;
    const int mlp_blocks = (N_NODES + 127) / 128;   // 782

    // ---- layer 1: agg -> fused MLP ----
    k_agg_b<DIM_IN><<<agg_blocks, 256, 0, stream>>>(xb, off, csr, eps1, rst1, N_NODES);
    // h1 = relu(relu(rst1@w1a)@w1b) -> R3
    k_mlp<DIM_IN><<<mlp_blocks, 512, 0, stream>>>(rst1, w1a_t, w1b_t, R3, N_NODES);

    // ---- layer 2: agg -> fused MLP ----
    // rst2 = agg(h1) -> R12
    k_agg_b<DIM_H><<<agg_blocks, 256, 0, stream>>>(R3, off, csr, eps2, R12, N_NODES);
    // h2 = relu(relu(rst2@w2a)@w2b) -> R3
    k_mlp<DIM_H><<<mlp_blocks, 512, 0, stream>>>(R12, w2a_t, w2b_t, R3, N_NODES);

    // ---- classifier: out = h2 @ fc_w + fc_b ----
    dim3 g1(1, mlp_blocks);
    gemm_fc<<<g1, 256, 0, stream>>>(R3, fc_t, fc_b, out, N_NODES, DIM_H, DIM_C);
}

// Round 7
// 501.707 us; speedup vs baseline: 1.0672x; 1.0672x over previous
//
#include <hip/hip_runtime.h>

#define N_NODES 100000
#define N_EDGES 1600000
#define DIM_IN  128
#define DIM_H   256
#define DIM_C   40

#define NB   391     // buckets of 256 nodes
#define NBLK 391     // edge chunks of 4096
#define CHUNK 4096
#define ECAP 6144    // LDS edge-cache capacity in k_build (mean 4092, +32 sigma)

typedef unsigned short bf16_t;
typedef __attribute__((ext_vector_type(8))) short short8;
typedef __attribute__((ext_vector_type(4))) float f32x4;

__device__ __forceinline__ bf16_t f2b(float f) {
    unsigned int u = __float_as_uint(f);
    unsigned int r = (u + 0x7fffu + ((u >> 16) & 1u)) >> 16;
    return (bf16_t)r;
}
__device__ __forceinline__ float b2f(unsigned int h16) {
    return __uint_as_float(h16 << 16);
}

__device__ __forceinline__ void gl_lds16(const void* gsrc, void* ldst) {
    __builtin_amdgcn_global_load_lds(
        (const __attribute__((address_space(1))) void*)gsrc,
        (__attribute__((address_space(3))) void*)ldst,
        16, 0, 0);
}

// ---------------- CSR build, two-phase binned (5 kernels) ----------------

__global__ void k_bhist(const int* __restrict__ dst, int* __restrict__ cnt2, int e) {
    __shared__ int h[NB];
    int t = threadIdx.x, blk = blockIdx.x;
    for (int i = t; i < NB; i += 256) h[i] = 0;
    __syncthreads();
    int base = blk * CHUNK;
    int end = min(base + CHUNK, e);
    for (int i = base + t; i < end; i += 256)
        atomicAdd(&h[dst[i] >> 8], 1);
    __syncthreads();
    for (int i = t; i < NB; i += 256) cnt2[blk * NB + i] = h[i];
}

__global__ void k_bscanA(const int* __restrict__ cnt2, int* __restrict__ basep,
                         int* __restrict__ btot) {
    __shared__ int s[512];
    int t = threadIdx.x, b = blockIdx.x;
    int v = (t < NBLK) ? cnt2[t * NB + b] : 0;
    s[t] = v;
    __syncthreads();
    #pragma unroll
    for (int d = 1; d < 512; d <<= 1) {
        int tv = (t >= d) ? s[t - d] : 0;
        __syncthreads();
        s[t] += tv;
        __syncthreads();
    }
    if (t < NBLK) basep[t * NB + b] = s[t] - v;
    if (t == 511) btot[b] = s[511];
}

__global__ void k_bscan2(const int* __restrict__ btot, int* __restrict__ boff) {
    __shared__ int s[512];
    int t = threadIdx.x;
    int v = (t < NB) ? btot[t] : 0;
    s[t] = v;
    __syncthreads();
    #pragma unroll
    for (int d = 1; d < 512; d <<= 1) {
        int tv = (t >= d) ? s[t - d] : 0;
        __syncthreads();
        s[t] += tv;
        __syncthreads();
    }
    if (t < NB) boff[t] = s[t] - v;
    if (t == NB - 1) boff[NB] = s[t];
}

__global__ void k_bscatter(const int* __restrict__ src, const int* __restrict__ dst,
                           const int* __restrict__ basep, const int* __restrict__ boff,
                           int2* __restrict__ ebuf, int e) {
    __shared__ int cur[NB];
    int t = threadIdx.x, blk = blockIdx.x;
    for (int i = t; i < NB; i += 256) cur[i] = basep[blk * NB + i] + boff[i];
    __syncthreads();
    int base = blk * CHUNK;
    int end = min(base + CHUNK, e);
    for (int i = base + t; i < end; i += 256) {
        int sv = src[i], dv = dst[i];
        int pos = atomicAdd(&cur[dv >> 8], 1);
        ebuf[pos] = make_int2(sv, dv);
    }
}

// fused per-bucket: histogram + scan (-> final off, using boff as global base) +
// exact node-grouped scatter, with the ebuf segment cached in LDS.
__global__ __launch_bounds__(256) void k_build(const int2* __restrict__ ebuf,
                                               const int* __restrict__ boff,
                                               int* __restrict__ off,
                                               int* __restrict__ csr) {
    __shared__ int2 ec[ECAP];
    __shared__ int h[256];
    __shared__ int cur[256];
    int t = threadIdx.x, b = blockIdx.x;
    int node0 = b << 8;
    int e0 = boff[b], e1 = boff[b + 1];
    int ne = e1 - e0;
    bool fits = (ne <= ECAP);
    h[t] = 0;
    __syncthreads();
    if (fits) {
        for (int i = t; i < ne; i += 256) {
            int2 p = ebuf[e0 + i];
            ec[i] = p;
            atomicAdd(&h[p.y - node0], 1);
        }
    } else {
        for (int i = t; i < ne; i += 256)
            atomicAdd(&h[ebuf[e0 + i].y - node0], 1);
    }
    __syncthreads();
    int mydeg = h[t];
    // inclusive scan of h
    #pragma unroll
    for (int d = 1; d < 256; d <<= 1) {
        int tv = (t >= d) ? h[t - d] : 0;
        __syncthreads();
        h[t] += tv;
        __syncthreads();
    }
    int node = node0 + t;
    if (node < N_NODES) off[node + 1] = e0 + h[t];
    if (b == 0 && t == 0) off[0] = 0;
    cur[t] = e0 + h[t] - mydeg;   // exclusive base for this node
    __syncthreads();
    if (fits) {
        for (int i = t; i < ne; i += 256) {
            int2 p = ec[i];
            int pos = atomicAdd(&cur[p.y - node0], 1);
            csr[pos] = p.x;
        }
    } else {
        for (int i = t; i < ne; i += 256) {
            int2 p = ebuf[e0 + i];
            int pos = atomicAdd(&cur[p.y - node0], 1);
            csr[pos] = p.x;
        }
    }
}

// ---------------- converts ----------------

__global__ void k_cvt4(const float* __restrict__ in, bf16_t* __restrict__ out, int n4) {
    int i = blockIdx.x * 256 + threadIdx.x;
    if (i < n4) {
        float4 v = ((const float4*)in)[i];
        ushort4 o;
        o.x = f2b(v.x); o.y = f2b(v.y); o.z = f2b(v.z); o.w = f2b(v.w);
        ((ushort4*)out)[i] = o;
    }
}

// all 5 weight transposes+converts in one kernel: region = blockIdx.y
__global__ void k_wcvt(const float* __restrict__ w1a, const float* __restrict__ w1b,
                       const float* __restrict__ w2a, const float* __restrict__ w2b,
                       const float* __restrict__ fcw,
                       bf16_t* __restrict__ o1a, bf16_t* __restrict__ o1b,
                       bf16_t* __restrict__ o2a, bf16_t* __restrict__ o2b,
                       bf16_t* __restrict__ ofc) {
    int r = blockIdx.y;
    int idx = blockIdx.x * 256 + threadIdx.x;
    const float* in; bf16_t* out; int K, N, Npad;
    switch (r) {
        case 0: in = w1a; out = o1a; K = 128; N = 256; Npad = 256; break;
        case 1: in = w1b; out = o1b; K = 256; N = 256; Npad = 256; break;
        case 2: in = w2a; out = o2a; K = 256; N = 256; Npad = 256; break;
        case 3: in = w2b; out = o2b; K = 256; N = 256; Npad = 256; break;
        default: in = fcw; out = ofc; K = 256; N = 40;  Npad = 128; break;
    }
    if (idx >= Npad * K) return;
    int n = idx / K, k = idx - n * K;
    float v = (n < N) ? in[(size_t)k * N + n] : 0.f;
    out[idx] = f2b(v);
}

// ---------------- aggregation (bf16 rows, fp32 accumulate, bf16 out) ----------------
// one wave per node; 8-deep batched edge loop — at fabric random-line floor (R4/R5)

template <int D>
__global__ void k_agg_b(const bf16_t* __restrict__ h, const int* __restrict__ off,
                        const int* __restrict__ csr, const float* __restrict__ eps_p,
                        bf16_t* __restrict__ rst, int n) {
    constexpr int V = D / 64;  // 2 or 4
    int gid = blockIdx.x * blockDim.x + threadIdx.x;
    int u = gid >> 6;
    int lane = gid & 63;
    if (u >= n) return;

    float acc[V];
    #pragma unroll
    for (int j = 0; j < V; j++) acc[j] = 0.f;

    int r0 = off[u], r1 = off[u + 1];
    int r = r0;

    if constexpr (V == 2) {
        for (; r + 8 <= r1; r += 8) {
            int s[8];
            #pragma unroll
            for (int t = 0; t < 8; t++) s[t] = csr[r + t];
            unsigned int v[8];
            #pragma unroll
            for (int t = 0; t < 8; t++)
                v[t] = *(const unsigned int*)(h + (size_t)s[t] * D + lane * 2);
            #pragma unroll
            for (int t = 0; t < 8; t++) {
                acc[0] += b2f(v[t] & 0xffffu);
                acc[1] += b2f(v[t] >> 16);
            }
        }
        for (; r < r1; r++) {
            int s = csr[r];
            unsigned int v = *(const unsigned int*)(h + (size_t)s * D + lane * 2);
            acc[0] += b2f(v & 0xffffu);
            acc[1] += b2f(v >> 16);
        }
    } else {
        for (; r + 8 <= r1; r += 8) {
            int s[8];
            #pragma unroll
            for (int t = 0; t < 8; t++) s[t] = csr[r + t];
            uint2 v[8];
            #pragma unroll
            for (int t = 0; t < 8; t++)
                v[t] = *(const uint2*)(h + (size_t)s[t] * D + lane * 4);
            #pragma unroll
            for (int t = 0; t < 8; t++) {
                acc[0] += b2f(v[t].x & 0xffffu);
                acc[1] += b2f(v[t].x >> 16);
                acc[2] += b2f(v[t].y & 0xffffu);
                acc[3] += b2f(v[t].y >> 16);
            }
        }
        for (; r < r1; r++) {
            int s = csr[r];
            uint2 v = *(const uint2*)(h + (size_t)s * D + lane * 4);
            acc[0] += b2f(v.x & 0xffffu);
            acc[1] += b2f(v.x >> 16);
            acc[2] += b2f(v.y & 0xffffu);
            acc[3] += b2f(v.y >> 16);
        }
    }

    float ep = 1.0f + eps_p[0];
    const bf16_t* xrow = h + (size_t)u * D + lane * V;
    bf16_t* orow = rst + (size_t)u * D + lane * V;
    if constexpr (V == 2) {
        unsigned int v = *(const unsigned int*)xrow;
        float o0 = ep * b2f(v & 0xffffu) + acc[0];
        float o1 = ep * b2f(v >> 16) + acc[1];
        *(unsigned int*)orow = (unsigned int)f2b(o0) | ((unsigned int)f2b(o1) << 16);
    } else {
        uint2 v = *(const uint2*)xrow;
        float o0 = ep * b2f(v.x & 0xffffu) + acc[0];
        float o1 = ep * b2f(v.x >> 16) + acc[1];
        float o2 = ep * b2f(v.y & 0xffffu) + acc[2];
        float o3 = ep * b2f(v.y >> 16) + acc[3];
        uint2 ov;
        ov.x = (unsigned int)f2b(o0) | ((unsigned int)f2b(o1) << 16);
        ov.y = (unsigned int)f2b(o2) | ((unsigned int)f2b(o3) << 16);
        *(uint2*)orow = ov;
    }
}

// ---------------- fused 2-GEMM MLP, 64-row M-tile (2 blocks/CU) ----------------
// 256 threads = 4 waves; block computes 64 rows x 256 cols.
// Phase 1: t = relu(A_tile @ W1) -> Ts (LDS bf16, stride 264).
// Phase 2: H = relu(Ts @ W2). W1t/W2t are [256][K] bf16 (transposed).
// LDS: 4 + 16 + 33.8 = 53.8 KB -> 2 blocks/CU.

#define TS_STRIDE 264

template <int K1>
__global__ __launch_bounds__(256, 2) void k_mlp(
    const bf16_t* __restrict__ A, const bf16_t* __restrict__ W1t,
    const bf16_t* __restrict__ W2t, bf16_t* __restrict__ H, int M)
{
    __shared__ __align__(16) bf16_t As[64 * 32];        // 4 KB
    __shared__ __align__(16) bf16_t Bs[256 * 32];       // 16 KB
    __shared__ __align__(16) bf16_t Ts[64 * TS_STRIDE]; // 33.8 KB

    int tid = threadIdx.x;
    int wave = tid >> 6, lane = tid & 63;
    int l15 = lane & 15, quad = lane >> 4;
    int bm = blockIdx.x * 64;
    int wn = wave * 64;                  // each wave: all 64 rows x 64 cols

    f32x4 acc[4][4];
    #pragma unroll
    for (int i = 0; i < 4; i++)
        #pragma unroll
        for (int j = 0; j < 4; j++) acc[i][j] = 0.f;

    // ---- phase 1: t = relu(A @ W1) ----
    for (int k0 = 0; k0 < K1; k0 += 32) {
        {   // stage A tile 64x32: one 16B seg per thread
            int row = tid >> 2, k8 = (tid & 3) * 8;
            int gr = bm + row; if (gr >= M) gr = M - 1;
            gl_lds16(A + (size_t)gr * K1 + k0 + k8, &As[(wave * 64) * 8]);
        }
        // stage W1t tile 256x32: four 16B segs per thread
        #pragma unroll
        for (int l = 0; l < 4; l++) {
            int s = l * 256 + tid;
            int row = s >> 2, k8 = (s & 3) * 8;
            gl_lds16(W1t + (size_t)row * K1 + k0 + k8, &Bs[(size_t)(l * 256 + wave * 64) * 8]);
        }
        __syncthreads();

        short8 af[4], bfv[4];
        #pragma unroll
        for (int i = 0; i < 4; i++)
            af[i] = *(const short8*)&As[(i * 16 + l15) * 32 + quad * 8];
        #pragma unroll
        for (int j = 0; j < 4; j++)
            bfv[j] = *(const short8*)&Bs[(wn + j * 16 + l15) * 32 + quad * 8];

        #pragma unroll
        for (int i = 0; i < 4; i++)
            #pragma unroll
            for (int j = 0; j < 4; j++)
                acc[i][j] = __builtin_amdgcn_mfma_f32_16x16x32_bf16(af[i], bfv[j], acc[i][j], 0, 0, 0);
        __syncthreads();
    }

    // write relu(t) to Ts; C-layout: row = i*16 + quad*4 + r, col = wn + j*16 + l15
    #pragma unroll
    for (int i = 0; i < 4; i++)
        #pragma unroll
        for (int j = 0; j < 4; j++) {
            int row = i * 16 + quad * 4;
            int col = wn + j * 16 + l15;
            #pragma unroll
            for (int r = 0; r < 4; r++)
                Ts[(row + r) * TS_STRIDE + col] = f2b(fmaxf(acc[i][j][r], 0.f));
        }

    #pragma unroll
    for (int i = 0; i < 4; i++)
        #pragma unroll
        for (int j = 0; j < 4; j++) acc[i][j] = 0.f;
    __syncthreads();

    // ---- phase 2: H = relu(Ts @ W2) ----
    for (int k0 = 0; k0 < 256; k0 += 32) {
        #pragma unroll
        for (int l = 0; l < 4; l++) {
            int s = l * 256 + tid;
            int row = s >> 2, k8 = (s & 3) * 8;
            gl_lds16(W2t + (size_t)row * 256 + k0 + k8, &Bs[(size_t)(l * 256 + wave * 64) * 8]);
        }
        __syncthreads();

        short8 af[4], bfv[4];
        #pragma unroll
        for (int i = 0; i < 4; i++)
            af[i] = *(const short8*)&Ts[(i * 16 + l15) * TS_STRIDE + k0 + quad * 8];
        #pragma unroll
        for (int j = 0; j < 4; j++)
            bfv[j] = *(const short8*)&Bs[(wn + j * 16 + l15) * 32 + quad * 8];

        #pragma unroll
        for (int i = 0; i < 4; i++)
            #pragma unroll
            for (int j = 0; j < 4; j++)
                acc[i][j] = __builtin_amdgcn_mfma_f32_16x16x32_bf16(af[i], bfv[j], acc[i][j], 0, 0, 0);
        __syncthreads();
    }

    // epilogue
    #pragma unroll
    for (int j = 0; j < 4; j++) {
        int col = wn + j * 16 + l15;
        #pragma unroll
        for (int i = 0; i < 4; i++) {
            #pragma unroll
            for (int r = 0; r < 4; r++) {
                int rowg = bm + i * 16 + quad * 4 + r;
                if (rowg < M)
                    H[(size_t)rowg * 256 + col] = f2b(fmaxf(acc[i][j][r], 0.f));
            }
        }
    }
}

// ---------------- fc GEMM (m97 structure, 256 threads) ----------------

__global__ __launch_bounds__(256) void gemm_fc(
    const bf16_t* __restrict__ A, const bf16_t* __restrict__ Bt,
    const float* __restrict__ bias, float* __restrict__ C,
    int M, int K, int Nst)
{
    __shared__ __align__(16) bf16_t As[128 * 32];
    __shared__ __align__(16) bf16_t Bs[128 * 32];

    int tid = threadIdx.x;
    int wave = tid >> 6, lane = tid & 63;
    int l15 = lane & 15, quad = lane >> 4;
    int bm = blockIdx.y * 128, bn = blockIdx.x * 128;
    int wm = (wave >> 1) * 64, wn = (wave & 1) * 64;

    f32x4 acc[4][4];
    #pragma unroll
    for (int i = 0; i < 4; i++)
        #pragma unroll
        for (int j = 0; j < 4; j++) acc[i][j] = 0.f;

    for (int k0 = 0; k0 < K; k0 += 32) {
        #pragma unroll
        for (int iss = 0; iss < 2; iss++) {
            int s = iss * 256 + wave * 64 + lane;
            int row = s >> 2;
            int k8 = (s & 3) * 8;
            int ldsoff = (iss * 256 + wave * 64) * 8;

            int grA = bm + row; if (grA >= M) grA = M - 1;
            gl_lds16(A + (size_t)grA * K + k0 + k8, &As[ldsoff]);

            int grB = bn + row;
            gl_lds16(Bt + (size_t)grB * K + k0 + k8, &Bs[ldsoff]);
        }
        __syncthreads();

        short8 af[4], bfv[4];
        #pragma unroll
        for (int i = 0; i < 4; i++)
            af[i] = *(const short8*)&As[(wm + i * 16 + l15) * 32 + quad * 8];
        #pragma unroll
        for (int j = 0; j < 4; j++)
            bfv[j] = *(const short8*)&Bs[(wn + j * 16 + l15) * 32 + quad * 8];

        #pragma unroll
        for (int i = 0; i < 4; i++)
            #pragma unroll
            for (int j = 0; j < 4; j++)
                acc[i][j] = __builtin_amdgcn_mfma_f32_16x16x32_bf16(af[i], bfv[j], acc[i][j], 0, 0, 0);
        __syncthreads();
    }

    #pragma unroll
    for (int j = 0; j < 4; j++) {
        int col = bn + wn + j * 16 + l15;
        if (col >= Nst) continue;
        float bv = bias[col];
        #pragma unroll
        for (int i = 0; i < 4; i++) {
            #pragma unroll
            for (int r = 0; r < 4; r++) {
                int rowg = bm + wm + i * 16 + quad * 4 + r;
                if (rowg < M)
                    C[(size_t)rowg * Nst + col] = acc[i][j][r] + bv;
            }
        }
    }
}

// ---------------- launch ----------------

static inline size_t rnd256(size_t x) { return (x + 255) & ~(size_t)255; }

extern "C" void kernel_launch(void* const* d_in, const int* in_sizes, int n_in,
                              void* d_out, int out_size, void* d_ws, size_t ws_size,
                              hipStream_t stream) {
    const float* x    = (const float*)d_in[0];
    const int*   src  = (const int*)d_in[1];
    const int*   dst  = (const int*)d_in[2];
    const float* eps1 = (const float*)d_in[3];
    const float* w1a  = (const float*)d_in[4];
    const float* w1b  = (const float*)d_in[5];
    const float* eps2 = (const float*)d_in[6];
    const float* w2a  = (const float*)d_in[7];
    const float* w2b  = (const float*)d_in[8];
    const float* fc_w = (const float*)d_in[9];
    const float* fc_b = (const float*)d_in[10];
    float* out = (float*)d_out;

    char* w = (char*)d_ws;
    int* off  = (int*)w; w += rnd256(sizeof(int) * (size_t)(N_NODES + 1));
    int* csr  = (int*)w; w += rnd256(sizeof(int) * (size_t)N_EDGES);
    int* cnt2  = (int*)w; w += rnd256(sizeof(int) * (size_t)NBLK * NB);
    int* basep = (int*)w; w += rnd256(sizeof(int) * (size_t)NBLK * NB);
    int* btot  = (int*)w; w += rnd256(sizeof(int) * 512);
    int* boff  = (int*)w; w += rnd256(sizeof(int) * (NB + 1));
    bf16_t* w1a_t = (bf16_t*)w; w += rnd256(2 * (size_t)DIM_H * DIM_IN);
    bf16_t* w1b_t = (bf16_t*)w; w += rnd256(2 * (size_t)DIM_H * DIM_H);
    bf16_t* w2a_t = (bf16_t*)w; w += rnd256(2 * (size_t)DIM_H * DIM_H);
    bf16_t* w2b_t = (bf16_t*)w; w += rnd256(2 * (size_t)DIM_H * DIM_H);
    bf16_t* fc_t  = (bf16_t*)w; w += rnd256(2 * (size_t)128 * DIM_H);
    bf16_t* R12 = (bf16_t*)w; w += rnd256(2 * (size_t)N_NODES * DIM_H);
    bf16_t* R3  = (bf16_t*)w; w += rnd256(2 * (size_t)N_NODES * DIM_H);

    bf16_t* xb   = R12;                             // [N][128]
    bf16_t* rst1 = R12 + (size_t)N_NODES * DIM_IN;  // [N][128]
    int2* ebuf = (int2*)R3;   // dead before k_mlp layer-1 writes R3

    // ---- CSR build ----
    k_bhist<<<NBLK, 256, 0, stream>>>(dst, cnt2, N_EDGES);
    k_bscanA<<<NB, 512, 0, stream>>>(cnt2, basep, btot);
    k_bscan2<<<1, 512, 0, stream>>>(btot, boff);
    k_bscatter<<<NBLK, 256, 0, stream>>>(src, dst, basep, boff, ebuf, N_EDGES);
    k_build<<<NB, 256, 0, stream>>>(ebuf, boff, off, csr);

    // ---- converts ----
    k_cvt4<<<(N_NODES * DIM_IN / 4 + 255) / 256, 256, 0, stream>>>(x, xb, N_NODES * DIM_IN / 4);
    {
        dim3 g(256, 5);
        k_wcvt<<<g, 256, 0, stream>>>(w1a, w1b, w2a, w2b, fc_w,
                                      w1a_t, w1b_t, w2a_t, w2b_t, fc_t);
    }

    const int agg_blocks = (N_NODES * 64 + 255) / 256;
    const int mlp_blocks = (N_NODES + 63) / 64;     // 1563

    // ---- layer 1 ----
    k_agg_b<DIM_IN><<<agg_blocks, 256, 0, stream>>>(xb, off, csr, eps1, rst1, N_NODES);
    k_mlp<DIM_IN><<<mlp_blocks, 256, 0, stream>>>(rst1, w1a_t, w1b_t, R3, N_NODES);

    // ---- layer 2 ----
    k_agg_b<DIM_H><<<agg_blocks, 256, 0, stream>>>(R3, off, csr, eps2, R12, N_NODES);
    k_mlp<DIM_H><<<mlp_blocks, 256, 0, stream>>>(R12, w2a_t, w2b_t, R3, N_NODES);

    // ---- classifier ----
    dim3 g1(1, (N_NODES + 127) / 128);
    gemm_fc<<<g1, 256, 0, stream>>>(R3, fc_t, fc_b, out, N_NODES, DIM_H, DIM_C);
}

// Round 8
// 464.788 us; speedup vs baseline: 1.1520x; 1.0794x over previous
//
#include <hip/hip_runtime.h>

#define N_NODES 100000
#define N_EDGES 1600000
#define DIM_IN  128
#define DIM_H   256
#define DIM_C   40

#define NB   391     // buckets of 256 nodes
#define NBLK 391     // edge chunks of 4096
#define CHUNK 4096
#define ECAP 6144    // LDS edge-cache capacity in k_build

typedef unsigned short bf16_t;
typedef __attribute__((ext_vector_type(8))) short short8;
typedef __attribute__((ext_vector_type(4))) float f32x4;

__device__ __forceinline__ bf16_t f2b(float f) {
    unsigned int u = __float_as_uint(f);
    unsigned int r = (u + 0x7fffu + ((u >> 16) & 1u)) >> 16;
    return (bf16_t)r;
}
__device__ __forceinline__ float b2f(unsigned int h16) {
    return __uint_as_float(h16 << 16);
}

__device__ __forceinline__ void gl_lds16(const void* gsrc, void* ldst) {
    __builtin_amdgcn_global_load_lds(
        (const __attribute__((address_space(1))) void*)gsrc,
        (__attribute__((address_space(3))) void*)ldst,
        16, 0, 0);
}

// ---------------- CSR build, two-phase binned ----------------

__global__ void k_bhist(const int* __restrict__ dst, int* __restrict__ cnt2, int e) {
    __shared__ int h[NB];
    int t = threadIdx.x, blk = blockIdx.x;
    for (int i = t; i < NB; i += 256) h[i] = 0;
    __syncthreads();
    int base = blk * CHUNK;
    int end = min(base + CHUNK, e);
    for (int i = base + t; i < end; i += 256)
        atomicAdd(&h[dst[i] >> 8], 1);
    __syncthreads();
    for (int i = t; i < NB; i += 256) cnt2[blk * NB + i] = h[i];
}

__global__ void k_bscanA(const int* __restrict__ cnt2, int* __restrict__ basep,
                         int* __restrict__ btot) {
    __shared__ int s[512];
    int t = threadIdx.x, b = blockIdx.x;
    int v = (t < NBLK) ? cnt2[t * NB + b] : 0;
    s[t] = v;
    __syncthreads();
    #pragma unroll
    for (int d = 1; d < 512; d <<= 1) {
        int tv = (t >= d) ? s[t - d] : 0;
        __syncthreads();
        s[t] += tv;
        __syncthreads();
    }
    if (t < NBLK) basep[t * NB + b] = s[t] - v;
    if (t == 511) btot[b] = s[511];
}

__global__ void k_bscan2(const int* __restrict__ btot, int* __restrict__ boff) {
    __shared__ int s[512];
    int t = threadIdx.x;
    int v = (t < NB) ? btot[t] : 0;
    s[t] = v;
    __syncthreads();
    #pragma unroll
    for (int d = 1; d < 512; d <<= 1) {
        int tv = (t >= d) ? s[t - d] : 0;
        __syncthreads();
        s[t] += tv;
        __syncthreads();
    }
    if (t < NB) boff[t] = s[t] - v;
    if (t == NB - 1) boff[NB] = s[t];
}

__global__ void k_bscatter(const int* __restrict__ src, const int* __restrict__ dst,
                           const int* __restrict__ basep, const int* __restrict__ boff,
                           int2* __restrict__ ebuf, int e) {
    __shared__ int cur[NB];
    int t = threadIdx.x, blk = blockIdx.x;
    for (int i = t; i < NB; i += 256) cur[i] = basep[blk * NB + i] + boff[i];
    __syncthreads();
    int base = blk * CHUNK;
    int end = min(base + CHUNK, e);
    for (int i = base + t; i < end; i += 256) {
        int sv = src[i], dv = dst[i];
        int pos = atomicAdd(&cur[dv >> 8], 1);
        ebuf[pos] = make_int2(sv, dv);
    }
}

__global__ __launch_bounds__(256) void k_build(const int2* __restrict__ ebuf,
                                               const int* __restrict__ boff,
                                               int* __restrict__ off,
                                               int* __restrict__ csr) {
    __shared__ int2 ec[ECAP];
    __shared__ int h[256];
    __shared__ int cur[256];
    int t = threadIdx.x, b = blockIdx.x;
    int node0 = b << 8;
    int e0 = boff[b], e1 = boff[b + 1];
    int ne = e1 - e0;
    bool fits = (ne <= ECAP);
    h[t] = 0;
    __syncthreads();
    if (fits) {
        for (int i = t; i < ne; i += 256) {
            int2 p = ebuf[e0 + i];
            ec[i] = p;
            atomicAdd(&h[p.y - node0], 1);
        }
    } else {
        for (int i = t; i < ne; i += 256)
            atomicAdd(&h[ebuf[e0 + i].y - node0], 1);
    }
    __syncthreads();
    int mydeg = h[t];
    #pragma unroll
    for (int d = 1; d < 256; d <<= 1) {
        int tv = (t >= d) ? h[t - d] : 0;
        __syncthreads();
        h[t] += tv;
        __syncthreads();
    }
    int node = node0 + t;
    if (node < N_NODES) off[node + 1] = e0 + h[t];
    if (b == 0 && t == 0) off[0] = 0;
    cur[t] = e0 + h[t] - mydeg;
    __syncthreads();
    if (fits) {
        for (int i = t; i < ne; i += 256) {
            int2 p = ec[i];
            int pos = atomicAdd(&cur[p.y - node0], 1);
            csr[pos] = p.x;
        }
    } else {
        for (int i = t; i < ne; i += 256) {
            int2 p = ebuf[e0 + i];
            int pos = atomicAdd(&cur[p.y - node0], 1);
            csr[pos] = p.x;
        }
    }
}

// ---------------- converts ----------------

__global__ void k_cvt4(const float* __restrict__ in, bf16_t* __restrict__ out, int n4) {
    int i = blockIdx.x * 256 + threadIdx.x;
    if (i < n4) {
        float4 v = ((const float4*)in)[i];
        ushort4 o;
        o.x = f2b(v.x); o.y = f2b(v.y); o.z = f2b(v.z); o.w = f2b(v.w);
        ((ushort4*)out)[i] = o;
    }
}

__global__ void k_wcvt(const float* __restrict__ w1a, const float* __restrict__ w1b,
                       const float* __restrict__ w2a, const float* __restrict__ w2b,
                       const float* __restrict__ fcw,
                       bf16_t* __restrict__ o1a, bf16_t* __restrict__ o1b,
                       bf16_t* __restrict__ o2a, bf16_t* __restrict__ o2b,
                       bf16_t* __restrict__ ofc) {
    int r = blockIdx.y;
    int idx = blockIdx.x * 256 + threadIdx.x;
    const float* in; bf16_t* out; int K, N, Npad;
    switch (r) {
        case 0: in = w1a; out = o1a; K = 128; N = 256; Npad = 256; break;
        case 1: in = w1b; out = o1b; K = 256; N = 256; Npad = 256; break;
        case 2: in = w2a; out = o2a; K = 256; N = 256; Npad = 256; break;
        case 3: in = w2b; out = o2b; K = 256; N = 256; Npad = 256; break;
        default: in = fcw; out = ofc; K = 256; N = 40;  Npad = 128; break;
    }
    if (idx >= Npad * K) return;
    int n = idx / K, k = idx - n * K;
    float v = (n < N) ? in[(size_t)k * N + n] : 0.f;
    out[idx] = f2b(v);
}

// ---------------- layer-1 aggregation (bf16 gather) ----------------

template <int D>
__global__ void k_agg_b(const bf16_t* __restrict__ h, const int* __restrict__ off,
                        const int* __restrict__ csr, const float* __restrict__ eps_p,
                        bf16_t* __restrict__ rst, int n) {
    constexpr int V = D / 64;  // 2 for 128
    int gid = blockIdx.x * blockDim.x + threadIdx.x;
    int u = gid >> 6;
    int lane = gid & 63;
    if (u >= n) return;

    float acc[V];
    #pragma unroll
    for (int j = 0; j < V; j++) acc[j] = 0.f;

    int r0 = off[u], r1 = off[u + 1];
    int r = r0;
    for (; r + 8 <= r1; r += 8) {
        int s[8];
        #pragma unroll
        for (int t = 0; t < 8; t++) s[t] = csr[r + t];
        unsigned int v[8];
        #pragma unroll
        for (int t = 0; t < 8; t++)
            v[t] = *(const unsigned int*)(h + (size_t)s[t] * D + lane * 2);
        #pragma unroll
        for (int t = 0; t < 8; t++) {
            acc[0] += b2f(v[t] & 0xffffu);
            acc[1] += b2f(v[t] >> 16);
        }
    }
    for (; r < r1; r++) {
        int s = csr[r];
        unsigned int v = *(const unsigned int*)(h + (size_t)s * D + lane * 2);
        acc[0] += b2f(v & 0xffffu);
        acc[1] += b2f(v >> 16);
    }

    float ep = 1.0f + eps_p[0];
    unsigned int v = *(const unsigned int*)(h + (size_t)u * D + lane * 2);
    float o0 = ep * b2f(v & 0xffffu) + acc[0];
    float o1 = ep * b2f(v >> 16) + acc[1];
    *(unsigned int*)(rst + (size_t)u * D + lane * 2) =
        (unsigned int)f2b(o0) | ((unsigned int)f2b(o1) << 16);
}

// ---------------- layer-2 aggregation (u8 row-scaled gather, D=256) ----------------
// one wave per node; lane covers 4 consecutive u8 cols (uint load)

__global__ void k_agg_u8(const unsigned char* __restrict__ h8,
                         const float* __restrict__ hs,
                         const int* __restrict__ off, const int* __restrict__ csr,
                         const float* __restrict__ eps_p,
                         bf16_t* __restrict__ rst, int n) {
    int gid = blockIdx.x * blockDim.x + threadIdx.x;
    int u = gid >> 6;
    int lane = gid & 63;
    if (u >= n) return;

    float acc[4] = {0.f, 0.f, 0.f, 0.f};
    int r0 = off[u], r1 = off[u + 1];
    int r = r0;
    for (; r + 8 <= r1; r += 8) {
        int s[8];
        #pragma unroll
        for (int t = 0; t < 8; t++) s[t] = csr[r + t];
        unsigned int v[8];
        float sc[8];
        #pragma unroll
        for (int t = 0; t < 8; t++) {
            v[t] = *(const unsigned int*)(h8 + (size_t)s[t] * 256 + lane * 4);
            sc[t] = hs[s[t]];
        }
        #pragma unroll
        for (int t = 0; t < 8; t++) {
            acc[0] += (float)(v[t] & 0xffu) * sc[t];
            acc[1] += (float)((v[t] >> 8) & 0xffu) * sc[t];
            acc[2] += (float)((v[t] >> 16) & 0xffu) * sc[t];
            acc[3] += (float)(v[t] >> 24) * sc[t];
        }
    }
    for (; r < r1; r++) {
        int s = csr[r];
        unsigned int v = *(const unsigned int*)(h8 + (size_t)s * 256 + lane * 4);
        float sc = hs[s];
        acc[0] += (float)(v & 0xffu) * sc;
        acc[1] += (float)((v >> 8) & 0xffu) * sc;
        acc[2] += (float)((v >> 16) & 0xffu) * sc;
        acc[3] += (float)(v >> 24) * sc;
    }

    float ep = 1.0f + eps_p[0];
    unsigned int vu = *(const unsigned int*)(h8 + (size_t)u * 256 + lane * 4);
    float scu = hs[u] * ep;
    float o0 = (float)(vu & 0xffu) * scu + acc[0];
    float o1 = (float)((vu >> 8) & 0xffu) * scu + acc[1];
    float o2 = (float)((vu >> 16) & 0xffu) * scu + acc[2];
    float o3 = (float)(vu >> 24) * scu + acc[3];
    uint2 ov;
    ov.x = (unsigned int)f2b(o0) | ((unsigned int)f2b(o1) << 16);
    ov.y = (unsigned int)f2b(o2) | ((unsigned int)f2b(o3) << 16);
    *(uint2*)(rst + (size_t)u * 256 + lane * 4) = ov;
}

// ---------------- fused 2-GEMM MLP, 64-row tile ----------------
// OUT8: write u8 + per-row scale (for u8 gather); else bf16.

#define TS_STRIDE 264

template <int K1, bool OUT8>
__global__ __launch_bounds__(256, 2) void k_mlp(
    const bf16_t* __restrict__ A, const bf16_t* __restrict__ W1t,
    const bf16_t* __restrict__ W2t, bf16_t* __restrict__ H,
    unsigned char* __restrict__ H8, float* __restrict__ Hs, int M)
{
    __shared__ __align__(16) bf16_t As[64 * 32];        // 4 KB
    __shared__ __align__(16) bf16_t Bs[256 * 32];       // 16 KB
    __shared__ __align__(16) bf16_t Ts[64 * TS_STRIDE]; // 33.8 KB
    __shared__ int rmax[64];

    int tid = threadIdx.x;
    int wave = tid >> 6, lane = tid & 63;
    int l15 = lane & 15, quad = lane >> 4;
    int bm = blockIdx.x * 64;
    int wn = wave * 64;

    f32x4 acc[4][4];
    #pragma unroll
    for (int i = 0; i < 4; i++)
        #pragma unroll
        for (int j = 0; j < 4; j++) acc[i][j] = 0.f;

    // ---- phase 1 ----
    for (int k0 = 0; k0 < K1; k0 += 32) {
        {
            int row = tid >> 2, k8 = (tid & 3) * 8;
            int gr = bm + row; if (gr >= M) gr = M - 1;
            gl_lds16(A + (size_t)gr * K1 + k0 + k8, &As[(wave * 64) * 8]);
        }
        #pragma unroll
        for (int l = 0; l < 4; l++) {
            int s = l * 256 + tid;
            int row = s >> 2, k8 = (s & 3) * 8;
            gl_lds16(W1t + (size_t)row * K1 + k0 + k8, &Bs[(size_t)(l * 256 + wave * 64) * 8]);
        }
        __syncthreads();

        short8 af[4], bfv[4];
        #pragma unroll
        for (int i = 0; i < 4; i++)
            af[i] = *(const short8*)&As[(i * 16 + l15) * 32 + quad * 8];
        #pragma unroll
        for (int j = 0; j < 4; j++)
            bfv[j] = *(const short8*)&Bs[(wn + j * 16 + l15) * 32 + quad * 8];

        #pragma unroll
        for (int i = 0; i < 4; i++)
            #pragma unroll
            for (int j = 0; j < 4; j++)
                acc[i][j] = __builtin_amdgcn_mfma_f32_16x16x32_bf16(af[i], bfv[j], acc[i][j], 0, 0, 0);
        __syncthreads();
    }

    #pragma unroll
    for (int i = 0; i < 4; i++)
        #pragma unroll
        for (int j = 0; j < 4; j++) {
            int row = i * 16 + quad * 4;
            int col = wn + j * 16 + l15;
            #pragma unroll
            for (int r = 0; r < 4; r++)
                Ts[(row + r) * TS_STRIDE + col] = f2b(fmaxf(acc[i][j][r], 0.f));
        }

    #pragma unroll
    for (int i = 0; i < 4; i++)
        #pragma unroll
        for (int j = 0; j < 4; j++) acc[i][j] = 0.f;
    __syncthreads();

    // ---- phase 2 ----
    for (int k0 = 0; k0 < 256; k0 += 32) {
        #pragma unroll
        for (int l = 0; l < 4; l++) {
            int s = l * 256 + tid;
            int row = s >> 2, k8 = (s & 3) * 8;
            gl_lds16(W2t + (size_t)row * 256 + k0 + k8, &Bs[(size_t)(l * 256 + wave * 64) * 8]);
        }
        __syncthreads();

        short8 af[4], bfv[4];
        #pragma unroll
        for (int i = 0; i < 4; i++)
            af[i] = *(const short8*)&Ts[(i * 16 + l15) * TS_STRIDE + k0 + quad * 8];
        #pragma unroll
        for (int j = 0; j < 4; j++)
            bfv[j] = *(const short8*)&Bs[(wn + j * 16 + l15) * 32 + quad * 8];

        #pragma unroll
        for (int i = 0; i < 4; i++)
            #pragma unroll
            for (int j = 0; j < 4; j++)
                acc[i][j] = __builtin_amdgcn_mfma_f32_16x16x32_bf16(af[i], bfv[j], acc[i][j], 0, 0, 0);
        __syncthreads();
    }

    if constexpr (OUT8) {
        // per-row max via LDS atomicMax (values >= 0: float bits order as int)
        if (tid < 64) rmax[tid] = 0;
        __syncthreads();
        #pragma unroll
        for (int i = 0; i < 4; i++)
            #pragma unroll
            for (int r = 0; r < 4; r++) {
                float m = 0.f;
                #pragma unroll
                for (int j = 0; j < 4; j++) m = fmaxf(m, acc[i][j][r]);
                atomicMax(&rmax[i * 16 + quad * 4 + r], __float_as_int(m));
            }
        __syncthreads();
        #pragma unroll
        for (int i = 0; i < 4; i++) {
            #pragma unroll
            for (int r = 0; r < 4; r++) {
                int row = i * 16 + quad * 4 + r;
                int rowg = bm + row;
                if (rowg >= M) continue;
                float rm = __int_as_float(rmax[row]);
                float inv = (rm > 0.f) ? 255.f / rm : 0.f;
                #pragma unroll
                for (int j = 0; j < 4; j++) {
                    int col = wn + j * 16 + l15;
                    float v = fmaxf(acc[i][j][r], 0.f);
                    unsigned q = (unsigned)(v * inv + 0.5f);
                    if (q > 255u) q = 255u;
                    H8[(size_t)rowg * 256 + col] = (unsigned char)q;
                }
                if (wave == 0 && l15 == 0)
                    Hs[rowg] = rm * (1.f / 255.f);
            }
        }
    } else {
        #pragma unroll
        for (int j = 0; j < 4; j++) {
            int col = wn + j * 16 + l15;
            #pragma unroll
            for (int i = 0; i < 4; i++) {
                #pragma unroll
                for (int r = 0; r < 4; r++) {
                    int rowg = bm + i * 16 + quad * 4 + r;
                    if (rowg < M)
                        H[(size_t)rowg * 256 + col] = f2b(fmaxf(acc[i][j][r], 0.f));
                }
            }
        }
    }
}

// ---------------- fc GEMM ----------------

__global__ __launch_bounds__(256) void gemm_fc(
    const bf16_t* __restrict__ A, const bf16_t* __restrict__ Bt,
    const float* __restrict__ bias, float* __restrict__ C,
    int M, int K, int Nst)
{
    __shared__ __align__(16) bf16_t As[128 * 32];
    __shared__ __align__(16) bf16_t Bs[128 * 32];

    int tid = threadIdx.x;
    int wave = tid >> 6, lane = tid & 63;
    int l15 = lane & 15, quad = lane >> 4;
    int bm = blockIdx.y * 128, bn = blockIdx.x * 128;
    int wm = (wave >> 1) * 64, wn = (wave & 1) * 64;

    f32x4 acc[4][4];
    #pragma unroll
    for (int i = 0; i < 4; i++)
        #pragma unroll
        for (int j = 0; j < 4; j++) acc[i][j] = 0.f;

    for (int k0 = 0; k0 < K; k0 += 32) {
        #pragma unroll
        for (int iss = 0; iss < 2; iss++) {
            int s = iss * 256 + wave * 64 + lane;
            int row = s >> 2;
            int k8 = (s & 3) * 8;
            int ldsoff = (iss * 256 + wave * 64) * 8;

            int grA = bm + row; if (grA >= M) grA = M - 1;
            gl_lds16(A + (size_t)grA * K + k0 + k8, &As[ldsoff]);

            int grB = bn + row;
            gl_lds16(Bt + (size_t)grB * K + k0 + k8, &Bs[ldsoff]);
        }
        __syncthreads();

        short8 af[4], bfv[4];
        #pragma unroll
        for (int i = 0; i < 4; i++)
            af[i] = *(const short8*)&As[(wm + i * 16 + l15) * 32 + quad * 8];
        #pragma unroll
        for (int j = 0; j < 4; j++)
            bfv[j] = *(const short8*)&Bs[(wn + j * 16 + l15) * 32 + quad * 8];

        #pragma unroll
        for (int i = 0; i < 4; i++)
            #pragma unroll
            for (int j = 0; j < 4; j++)
                acc[i][j] = __builtin_amdgcn_mfma_f32_16x16x32_bf16(af[i], bfv[j], acc[i][j], 0, 0, 0);
        __syncthreads();
    }

    #pragma unroll
    for (int j = 0; j < 4; j++) {
        int col = bn + wn + j * 16 + l15;
        if (col >= Nst) continue;
        float bv = bias[col];
        #pragma unroll
        for (int i = 0; i < 4; i++) {
            #pragma unroll
            for (int r = 0; r < 4; r++) {
                int rowg = bm + wm + i * 16 + quad * 4 + r;
                if (rowg < M)
                    C[(size_t)rowg * Nst + col] = acc[i][j][r] + bv;
            }
        }
    }
}

// ---------------- launch ----------------

static inline size_t rnd256(size_t x) { return (x + 255) & ~(size_t)255; }

extern "C" void kernel_launch(void* const* d_in, const int* in_sizes, int n_in,
                              void* d_out, int out_size, void* d_ws, size_t ws_size,
                              hipStream_t stream) {
    const float* x    = (const float*)d_in[0];
    const int*   src  = (const int*)d_in[1];
    const int*   dst  = (const int*)d_in[2];
    const float* eps1 = (const float*)d_in[3];
    const float* w1a  = (const float*)d_in[4];
    const float* w1b  = (const float*)d_in[5];
    const float* eps2 = (const float*)d_in[6];
    const float* w2a  = (const float*)d_in[7];
    const float* w2b  = (const float*)d_in[8];
    const float* fc_w = (const float*)d_in[9];
    const float* fc_b = (const float*)d_in[10];
    float* out = (float*)d_out;

    char* w = (char*)d_ws;
    int* off  = (int*)w; w += rnd256(sizeof(int) * (size_t)(N_NODES + 1));
    int* csr  = (int*)w; w += rnd256(sizeof(int) * (size_t)N_EDGES);
    int* cnt2  = (int*)w; w += rnd256(sizeof(int) * (size_t)NBLK * NB);
    int* basep = (int*)w; w += rnd256(sizeof(int) * (size_t)NBLK * NB);
    int* btot  = (int*)w; w += rnd256(sizeof(int) * 512);
    int* boff  = (int*)w; w += rnd256(sizeof(int) * (NB + 1));
    bf16_t* w1a_t = (bf16_t*)w; w += rnd256(2 * (size_t)DIM_H * DIM_IN);
    bf16_t* w1b_t = (bf16_t*)w; w += rnd256(2 * (size_t)DIM_H * DIM_H);
    bf16_t* w2a_t = (bf16_t*)w; w += rnd256(2 * (size_t)DIM_H * DIM_H);
    bf16_t* w2b_t = (bf16_t*)w; w += rnd256(2 * (size_t)DIM_H * DIM_H);
    bf16_t* fc_t  = (bf16_t*)w; w += rnd256(2 * (size_t)128 * DIM_H);
    unsigned char* h8 = (unsigned char*)w; w += rnd256((size_t)N_NODES * DIM_H);
    float* hs = (float*)w; w += rnd256(sizeof(float) * (size_t)N_NODES);
    bf16_t* R12 = (bf16_t*)w; w += rnd256(2 * (size_t)N_NODES * DIM_H);
    bf16_t* R3  = (bf16_t*)w; w += rnd256(2 * (size_t)N_NODES * DIM_H);

    bf16_t* xb   = R12;                             // [N][128]
    bf16_t* rst1 = R12 + (size_t)N_NODES * DIM_IN;  // [N][128]
    int2* ebuf = (int2*)R3;   // dead before layer-2 agg writes R3

    // ---- CSR build ----
    k_bhist<<<NBLK, 256, 0, stream>>>(dst, cnt2, N_EDGES);
    k_bscanA<<<NB, 512, 0, stream>>>(cnt2, basep, btot);
    k_bscan2<<<1, 512, 0, stream>>>(btot, boff);
    k_bscatter<<<NBLK, 256, 0, stream>>>(src, dst, basep, boff, ebuf, N_EDGES);
    k_build<<<NB, 256, 0, stream>>>(ebuf, boff, off, csr);

    // ---- converts ----
    k_cvt4<<<(N_NODES * DIM_IN / 4 + 255) / 256, 256, 0, stream>>>(x, xb, N_NODES * DIM_IN / 4);
    {
        dim3 g(256, 5);
        k_wcvt<<<g, 256, 0, stream>>>(w1a, w1b, w2a, w2b, fc_w,
                                      w1a_t, w1b_t, w2a_t, w2b_t, fc_t);
    }

    const int agg_blocks = (N_NODES * 64 + 255) / 256;
    const int mlp_blocks = (N_NODES + 63) / 64;

    // ---- layer 1: bf16 agg -> MLP (u8 output + row scales) ----
    k_agg_b<DIM_IN><<<agg_blocks, 256, 0, stream>>>(xb, off, csr, eps1, rst1, N_NODES);
    k_mlp<DIM_IN, true><<<mlp_blocks, 256, 0, stream>>>(rst1, w1a_t, w1b_t,
                                                        nullptr, h8, hs, N_NODES);

    // ---- layer 2: u8 agg -> MLP (bf16 output) ----
    k_agg_u8<<<agg_blocks, 256, 0, stream>>>(h8, hs, off, csr, eps2, (bf16_t*)R3, N_NODES);
    k_mlp<DIM_H, false><<<mlp_blocks, 256, 0, stream>>>((bf16_t*)R3, w2a_t, w2b_t,
                                                        R12, nullptr, nullptr, N_NODES);

    // ---- classifier ----
    dim3 g1(1, (N_NODES + 127) / 128);
    gemm_fc<<<g1, 256, 0, stream>>>(R12, fc_t, fc_b, out, N_NODES, DIM_H, DIM_C);
}